// Round 8
// baseline (196.951 us; speedup 1.0000x reference)
//
#include <hip/hip_runtime.h>

// Problem constants (B, C, H, W = 64, 2048, 24, 8; NUM_IDS = 751)
#define BB 64
#define CC 2048
#define HWN 192          // H*W
#define HW4 48           // HW in float4
#define NCHUNK 16        // channel chunks per sample (partial slots)
#define CCHUNK 128       // CC / NCHUNK
#define K1TPB 192        // 4 channel-groups x 48 hw4 positions
#define TPB 384          // K2 block
#define SCHUNK 16        // scale chunks per sample
#define SCCH 128         // CC / SCHUNK

// native vector type (HIP float4 is a class; nontemporal builtin needs this)
typedef float f32x4 __attribute__((ext_vector_type(4)));

// ws layout (floats): partial[64][16][192]
#define PART_OFF 0

// ---- Kernel 1: partial heat, pure-stream hot loop ----
// grid = 1024 (b*16 + k), block = 192. Thread tid: position p = tid%48,
// channel-group co = tid/48. Iteration i covers channels 4i..4i+3; thread's
// f4 address is fb4[192*i + tid] -> every wave instruction reads 1 KB
// contiguous. Weights live in 32 VGPRs (preloaded, no LDS, no barrier);
// hot loop is {global_load_dwordx4 ; 4x v_fmac} only.
__global__ void __launch_bounds__(K1TPB) heat_partial_kernel(
    const float* __restrict__ f,
    const float* __restrict__ w,
    const int* __restrict__ pids,
    float* __restrict__ ws)
{
    float* partial = ws + PART_OFF;

    const int blk = blockIdx.x;
    const int b = blk >> 4;            // sample
    const int k = blk & (NCHUNK - 1);  // 128-channel chunk
    const int tid = threadIdx.x;       // 0..191
    const int co  = tid / HW4;         // 0..3 channel offset within group of 4

    const int row = pids[b];
    // this thread's weights: w_row[k*128 + co + 4*i], i = 0..31
    const float* wr = w + (size_t)row * CC + (size_t)k * CCHUNK + co;
    float wv[32];
#pragma unroll
    for (int i = 0; i < 32; ++i) wv[i] = wr[4 * i];   // 48-lane broadcast loads

    const size_t base = ((size_t)b * CC + (size_t)k * CCHUNK) * HW4;  // f4 units
    const f32x4* fb4 = (const f32x4*)f + base;

    f32x4 acc = (f32x4)(0.f);
#pragma unroll
    for (int i = 0; i < 32; ++i)                      // 32 x 1KB/wave, linear
        acc += wv[i] * fb4[192 * i + tid];

    // 4-way cross-group reduce (only sync in the kernel)
    __shared__ __align__(16) f32x4 red[K1TPB];
    red[tid] = acc;
    __syncthreads();
    if (tid < HW4) {
        f32x4 s = red[tid] + red[tid + 48] + red[tid + 96] + red[tid + 144];
        ((f32x4*)partial)[(size_t)(b * NCHUNK + k) * HW4 + tid] = s;
    }
}

// ---- Kernel 2: fused normalize + scale (proven at roofline; unchanged) ----
// grid = 1024 (b*16 + k), block = 384. Prologue: redundant per-block reduce of
// this sample's 16 partials (12 KB, L2/L3-hot), min/max, normalize in LDS.
// Then pure stream: out = f * heatN with nontemporal stores.
__global__ void __launch_bounds__(TPB) norm_scale_kernel(
    const float* __restrict__ f,
    const float* __restrict__ ws,
    float* __restrict__ out)
{
    const float* partial = ws + PART_OFF;

    const int blk = blockIdx.x;
    const int b = blk >> 4;            // sample
    const int k = blk & (SCHUNK - 1);  // 128-channel chunk
    const int tid = threadIdx.x;       // 0..383
    const int hw4 = tid % HW4;

    __shared__ float vals[HWN];
    __shared__ __align__(16) float hl[HWN];
    __shared__ float s_mn, s_mx;

    float v = 0.f;
    if (tid < HWN) {
        const float* pb = partial + (size_t)b * NCHUNK * HWN + tid;
#pragma unroll
        for (int kk = 0; kk < NCHUNK; ++kk) v += pb[kk * HWN];
        vals[tid] = v;
    }
    __syncthreads();
    if (tid < 64) {
        float m0 = vals[tid], m1 = vals[tid + 64], m2 = vals[tid + 128];
        float mn = fminf(m0, fminf(m1, m2));
        float mx = fmaxf(m0, fmaxf(m1, m2));
        for (int off = 32; off > 0; off >>= 1) {
            mn = fminf(mn, __shfl_down(mn, off));
            mx = fmaxf(mx, __shfl_down(mx, off));
        }
        if (tid == 0) { s_mn = mn; s_mx = mx; }
    }
    __syncthreads();
    if (tid < HWN) {
        const float mn = s_mn, mx = s_mx;
        // reference: normalize only if max != 0
        hl[tid] = (mx != 0.f) ? (v - mn) / (mx - mn) : v;
    }
    __syncthreads();

    // stream this block's 128-channel chunk
    const f32x4 hv = ((const f32x4*)hl)[hw4];          // loop-invariant
    const size_t base = ((size_t)b * CC + (size_t)k * SCCH) * HW4;  // f4 units
    const f32x4* fb4 = (const f32x4*)f + base;
    f32x4* ob4 = (f32x4*)out + base;
#pragma unroll
    for (int i = 0; i < (SCCH * HW4) / TPB; ++i) {     // 16 linear iters
        const size_t idx = (size_t)i * TPB + tid;
        f32x4 x = fb4[idx];
        x *= hv;
        __builtin_nontemporal_store(x, &ob4[idx]);     // out never re-read
    }
}

extern "C" void kernel_launch(void* const* d_in, const int* in_sizes, int n_in,
                              void* d_out, int out_size, void* d_ws, size_t ws_size,
                              hipStream_t stream) {
    const float* features = (const float*)d_in[0];   // [64,2048,24,8] f32
    const float* weight   = (const float*)d_in[1];   // [751,2048] f32
    const int*   pids     = (const int*)d_in[2];     // [64] int
    float* out = (float*)d_out;                      // [64,2048,24,8] f32
    float* ws  = (float*)d_ws;

    heat_partial_kernel<<<BB * NCHUNK, K1TPB, 0, stream>>>(features, weight, pids, ws);
    norm_scale_kernel<<<BB * SCHUNK, TPB, 0, stream>>>(features, ws, out);
}